// Round 19
// baseline (78.442 us; speedup 1.0000x reference)
//
#include <hip/hip_runtime.h>
#include <hip/hip_bf16.h>
#include <stdint.h>

// ---- problem constants ----
#define BBATCH 4
#define NSEQ   256
#define DIN    64
#define DOUT   128
#define NBASIS 8
#define KTOT   576   // 64 base (silu) + 64*8 spline features
#define K2TOT  1152  // two KANs worth of features for the final stage
#define NSTEP  18    // 576/32
#define XST16  68    // u16 stride for bf16 X rows: 136B, 8B-aligned, 2-way-free banks

typedef __attribute__((ext_vector_type(8))) __bf16 bf16x8;
typedef __attribute__((ext_vector_type(4))) float  f32x4;

__device__ __forceinline__ float wave_sum(float v){
#pragma unroll
  for (int m = 1; m < 64; m <<= 1) v += __shfl_xor(v, m, 64);
  return v;
}

__device__ __forceinline__ float fast_tanh(float y){
  y = fminf(10.f, fmaxf(-10.f, y));
  float e = __expf(2.f * y);
  return (e - 1.f) / (e + 1.f);
}

__device__ __forceinline__ float silu_f(float x){
  return __fdividef(x, 1.f + __expf(-x));
}

__device__ __forceinline__ unsigned short f2bf(float f){
  union { float f; unsigned u; } v; v.f = f;
  unsigned r = (v.u + 0x7fffu + ((v.u >> 16) & 1u)) >> 16;
  return (unsigned short)r;
}

__device__ __forceinline__ float bf2f(unsigned short s){
  union { unsigned u; float f; } v; v.u = ((unsigned)s) << 16;
  return v.f;
}

__device__ __forceinline__ float bf2f_lo(unsigned w){
  union { unsigned u; float f; } v; v.u = w << 16;
  return v.f;
}
__device__ __forceinline__ float bf2f_hi(unsigned w){
  union { unsigned u; float f; } v; v.u = w & 0xffff0000u;
  return v.f;
}

// pack two f32 -> one u32 of 2 bf16 (round-half-up) via v_perm_b32
__device__ __forceinline__ unsigned pk2(float a, float b){
  union { float f; unsigned u; } ua, ub; ua.f = a; ub.f = b;
  return __builtin_amdgcn_perm(ub.u + 0x8000u, ua.u + 0x8000u, 0x07060302);
}

// uniform cubic B-spline: grid [-1,1] step h=0.4, extended by 3 knots each side.
__device__ __forceinline__ void spline_w(float x, int &i, float w[4]){
  float u = (x + 1.f) * 2.5f;
  int ii = (int)floorf(u);
  ii = ii < 0 ? 0 : (ii > 5 ? 5 : ii);
  float t = u - (float)ii;
  float t2 = t * t, t3 = t2 * t;
  float it = 1.f - t;
  w[0] = it * it * it * (1.f/6.f);
  w[1] = (3.f*t3 - 6.f*t2 + 4.f) * (1.f/6.f);
  w[2] = (-3.f*t3 + 3.f*t2 + 3.f*t + 1.f) * (1.f/6.f);
  w[3] = t3 * (1.f/6.f);
  i = ii;
}

// full 8-slot packed spline basis row (bf16x8) for one x, in-register.
// w0..w3 land at slots i..i+3; slot 8 (i=5,k=3) falls off the shift: dropped,
// matching the reference's 8-basis truncation.
__device__ __forceinline__ bf16x8 spline_pack(float x){
  float u = (x + 1.f) * 2.5f;
  int ii = (int)floorf(u);
  ii = ii < 0 ? 0 : (ii > 5 ? 5 : ii);
  float t = u - (float)ii;
  float t2 = t * t, t3 = t2 * t;
  float it = 1.f - t;
  float w0 = it * it * it * (1.f/6.f);
  float w1 = (3.f*t3 - 6.f*t2 + 4.f) * (1.f/6.f);
  float w2 = (-3.f*t3 + 3.f*t2 + 3.f*t + 1.f) * (1.f/6.f);
  float w3 = t3 * (1.f/6.f);
  unsigned long long W = ((unsigned long long)pk2(w2, w3) << 32) | (unsigned long long)pk2(w0, w1);
  int s16 = ii << 4;
  unsigned long long shl_lo = W << (s16 & 63);
  unsigned long long shr    = W >> ((64 - s16) & 63);
  unsigned long long shl_hi = W << ((s16 - 64) & 63);
  bool ge4 = ii >= 4;
  unsigned long long lo = ge4 ? 0ull : shl_lo;
  unsigned long long hi = ge4 ? shl_hi : (ii == 0 ? 0ull : shr);
  union { unsigned long long q[2]; bf16x8 v8; } r;
  r.q[0] = lo; r.q[1] = hi;
  return r.v8;
}

// ---------- kernel A: fused prep (rows + S + wm + S2) ----------
// S_t in MFMA-fragment order (R17 win): S_t[((s*4+nt)*64 + lane)*8 + e]
// holds S[o=nt*16+(lane&15)][k=s*32+(lane>>4)*8+e] -> wave loads are dense.
// S2 fragment order (R18 win): S2f[(jj*128 + o)*8 + e] holds S2[o][kk=jj*8+e].
__global__ void k_prep_all(const float* __restrict__ h,
                           const float* __restrict__ g_in, const float* __restrict__ b_in,
                           const float* __restrict__ ka_bw, const float* __restrict__ ka_sw,
                           const float* __restrict__ ka_c,  const float* __restrict__ W_att,
                           const float* __restrict__ kp_bw, const float* __restrict__ kp_sw,
                           const float* __restrict__ kp_c,
                           const float* __restrict__ kd_bw, const float* __restrict__ kd_sw,
                           const float* __restrict__ kd_c,
                           float* __restrict__ h_ln, float* __restrict__ hn,
                           unsigned short* __restrict__ S_t, float* __restrict__ wm,
                           unsigned short* __restrict__ S2){
  int blk = blockIdx.x, tid = threadIdx.x;
  if (blk < 256){                       // LN(h) + unit-norm: 4 rows/block
    int row = blk*4 + (tid >> 6);
    int d   = tid & 63;
    float x = h[row*DIN + d];
    float mean = wave_sum(x) * (1.f/64.f);
    float xm = x - mean;
    float var = wave_sum(xm*xm) * (1.f/64.f);
    float hl = xm * rsqrtf(var + 1e-5f) * g_in[d] + b_in[d];
    h_ln[row*DIN + d] = hl;
    float nrm = sqrtf(wave_sum(hl*hl));
    nrm = fmaxf(nrm, 1e-12f);
    hn[row*DIN + d] = hl / nrm;
  } else if (blk < 320){                // S_t in fragment order
    int o = blk - 256;
    int nt = o >> 4, colr = o & 15;
    for (int k = tid; k < KTOT; k += 256){
      float v;
      if (k < 64){
        v = ka_bw[o*64 + k];
      } else {
        int km = k - 64, dd = km >> 3, j = km & 7;
        float c = ka_c[(o*64 + dd)*8 + j];
        c = fminf(5.f, fmaxf(-5.f, c));
        v = c * ka_sw[o*64 + dd];
      }
      int s = k >> 5, grp = (k >> 3) & 3, e = k & 7;
      int lane = grp*16 + colr;
      S_t[((s*4 + nt)*64 + lane)*8 + e] = f2bf(v);
    }
  } else if (blk == 320){               // wm
    if (tid < 64){
      float s = 0.f;
      for (int k = 0; k < 256; ++k) s += W_att[tid*256 + k];
      wm[tid] = s * (1.f/256.f);
    }
  } else {                              // S2 fragment order
    int o = blk - 321;
    for (int kk = tid; kk < K2TOT; kk += 256){
      const float* bw; const float* sw; const float* cc;
      int k = kk;
      if (kk < KTOT){ bw = kp_bw; sw = kp_sw; cc = kp_c; }
      else          { bw = kd_bw; sw = kd_sw; cc = kd_c; k = kk - KTOT; }
      float v;
      if (k < 64){
        v = bw[o*64 + k];
      } else {
        int km = k - 64, d = km >> 3, j = km & 7;
        float c = cc[(o*64 + d)*8 + j];
        c = fminf(5.f, fmaxf(-5.f, c));
        v = c * sw[o*64 + d];
      }
      S2[((kk >> 3)*128 + o)*8 + (kk & 7)] = f2bf(v);
    }
  }
}

// ---------- kernel B: scores[b,n,m] — R17 (fragment-order B), unchanged ----------
__launch_bounds__(512, 4)
__global__ void k_scores(const float* __restrict__ hn,
                         const float* __restrict__ ln_p_g, const float* __restrict__ ln_p_b,
                         const unsigned short* __restrict__ S_t,
                         const float* __restrict__ wm,
                         float* __restrict__ scores){
  __shared__ unsigned short Xs[NSEQ * XST16];   // 256*68*2 = 34816 B
  __shared__ float hnn_l[64], g_l[64], b_l[64];

  int idx  = blockIdx.x;
  int bb   = idx & 3;            // heavy (small n) blocks dispatched first
  int n    = idx >> 2;
  int sn   = n >> 5;

  int tid  = threadIdx.x;
  int lane = tid & 63, wave = tid >> 6;   // 8 waves
  int m0   = wave * 32;
  bool active = (wave >= sn);

  // ---- phase 0: coalesced staging of this wave's 32 hn rows as bf16 ----
  if (active){
    const float* src = hn + (bb*NSEQ + m0)*DIN;
#pragma unroll
    for (int j = 0; j < 8; ++j){
      int f4 = j*64 + lane;                 // float4 index in wave's 2048 floats
      float4 v = *(const float4*)(src + f4*4);
      int r = f4 >> 4, c = (f4 & 15) * 4;
      uint2 pk = { pk2(v.x, v.y), pk2(v.z, v.w) };
      *(uint2*)(Xs + (m0 + r)*XST16 + c) = pk;
    }
  }
  if (wave == 7){                // wave 7 always active
    g_l[lane]   = ln_p_g[lane];
    b_l[lane]   = ln_p_b[lane];
    hnn_l[lane] = bf2f(f2bf(hn[(bb*NSEQ + n)*DIN + lane]));  // bf16-rounded: bitwise symmetry
  }
  __syncthreads();

  // ---- phase 1: per-thread LN + tanh, in place (2 threads/row, own rows) ----
  if (active){
    int r = tid >> 1, hh = tid & 1;          // r in [m0, m0+32) for this wave
    unsigned short* row = Xs + r*XST16 + hh*32;
    const float* hp = hnn_l + hh*32;
    float s1 = 0.f, s2 = 0.f;
#pragma unroll
    for (int i = 0; i < 8; ++i){
      uint2 ww = *(const uint2*)(row + i*4);
      float x0 = bf2f_lo(ww.x), x1 = bf2f_hi(ww.x), x2 = bf2f_lo(ww.y), x3 = bf2f_hi(ww.y);
      float p0 = x0*hp[i*4+0], p1 = x1*hp[i*4+1], p2 = x2*hp[i*4+2], p3 = x3*hp[i*4+3];
      s1 += (p0+p1) + (p2+p3);
      s2 = fmaf(p0,p0, fmaf(p1,p1, fmaf(p2,p2, fmaf(p3,p3, s2))));
    }
    s1 += __shfl_xor(s1, 1, 64);
    s2 += __shfl_xor(s2, 1, 64);
    float mean = s1 * (1.f/64.f);
    float var  = fmaxf(s2 * (1.f/64.f) - mean*mean, 0.f);
    float inv  = rsqrtf(var + 1e-5f);
    const float* gp = g_l + hh*32;
    const float* bp = b_l + hh*32;
#pragma unroll
    for (int i = 0; i < 8; ++i){
      uint2 ww = *(const uint2*)(row + i*4);
      float x0 = bf2f_lo(ww.x), x1 = bf2f_hi(ww.x), x2 = bf2f_lo(ww.y), x3 = bf2f_hi(ww.y);
      float t0 = fast_tanh((x0*hp[i*4+0] - mean)*inv*gp[i*4+0] + bp[i*4+0]);
      float t1 = fast_tanh((x1*hp[i*4+1] - mean)*inv*gp[i*4+1] + bp[i*4+1]);
      float t2 = fast_tanh((x2*hp[i*4+2] - mean)*inv*gp[i*4+2] + bp[i*4+2]);
      float t3 = fast_tanh((x3*hp[i*4+3] - mean)*inv*gp[i*4+3] + bp[i*4+3]);
      uint2 pk = { pk2(t0, t1), pk2(t2, t3) };
      *(uint2*)(row + i*4) = pk;
    }
  }
  __syncthreads();
  if (!active) return;            // no barriers after this point

  // ---- phase 2: MFMA K-loop, fragment-order B from global ----
  int colr = lane & 15, grp = lane >> 4;
  const unsigned short* rowA = Xs + (m0 + colr)*XST16;
  const unsigned short* rowB = Xs + (m0 + 16 + colr)*XST16;
  const unsigned short* sfp  = S_t + lane*8;   // + (s*4+nt)*512 per fragment

  f32x4 acc[2][4];
#pragma unroll
  for (int a = 0; a < 2; ++a)
#pragma unroll
    for (int c = 0; c < 4; ++c){ f32x4 z = {0.f,0.f,0.f,0.f}; acc[a][c] = z; }

  // silu steps (k = 0..63): lane's 8 k-slots = 8 dims
#pragma unroll
  for (int s = 0; s < 2; ++s){
    int kw = s*32 + grp*8;
    bf16x8 bf[4];
#pragma unroll
    for (int nt = 0; nt < 4; ++nt)
      bf[nt] = *(const bf16x8*)(sfp + (s*4 + nt)*512);
    union { unsigned u[4]; bf16x8 v8; } a0, a1;
    uint2 wa0 = *(const uint2*)(rowA + kw), wa1 = *(const uint2*)(rowA + kw + 4);
    uint2 wb0 = *(const uint2*)(rowB + kw), wb1 = *(const uint2*)(rowB + kw + 4);
    a0.u[0] = pk2(silu_f(bf2f_lo(wa0.x)), silu_f(bf2f_hi(wa0.x)));
    a0.u[1] = pk2(silu_f(bf2f_lo(wa0.y)), silu_f(bf2f_hi(wa0.y)));
    a0.u[2] = pk2(silu_f(bf2f_lo(wa1.x)), silu_f(bf2f_hi(wa1.x)));
    a0.u[3] = pk2(silu_f(bf2f_lo(wa1.y)), silu_f(bf2f_hi(wa1.y)));
    a1.u[0] = pk2(silu_f(bf2f_lo(wb0.x)), silu_f(bf2f_hi(wb0.x)));
    a1.u[1] = pk2(silu_f(bf2f_lo(wb0.y)), silu_f(bf2f_hi(wb0.y)));
    a1.u[2] = pk2(silu_f(bf2f_lo(wb1.x)), silu_f(bf2f_hi(wb1.x)));
    a1.u[3] = pk2(silu_f(bf2f_lo(wb1.y)), silu_f(bf2f_hi(wb1.y)));
#pragma unroll
    for (int nt = 0; nt < 4; ++nt){
      acc[0][nt] = __builtin_amdgcn_mfma_f32_16x16x32_bf16(a0.v8, bf[nt], acc[0][nt], 0, 0, 0);
      acc[1][nt] = __builtin_amdgcn_mfma_f32_16x16x32_bf16(a1.v8, bf[nt], acc[1][nt], 0, 0, 0);
    }
  }

  // spline steps (k = 64..575): lane's 8 k-slots = one dim's 8 bases
#pragma unroll 4
  for (int s = 2; s < NSTEP; ++s){
    int d  = (s - 2)*4 + grp;
    bf16x8 bf[4];
#pragma unroll
    for (int nt = 0; nt < 4; ++nt)
      bf[nt] = *(const bf16x8*)(sfp + (s*4 + nt)*512);
    bf16x8 a0 = spline_pack(bf2f(rowA[d]));
    bf16x8 a1 = spline_pack(bf2f(rowB[d]));
#pragma unroll
    for (int nt = 0; nt < 4; ++nt){
      acc[0][nt] = __builtin_amdgcn_mfma_f32_16x16x32_bf16(a0, bf[nt], acc[0][nt], 0, 0, 0);
      acc[1][nt] = __builtin_amdgcn_mfma_f32_16x16x32_bf16(a1, bf[nt], acc[1][nt], 0, 0, 0);
    }
  }

  // ---- epilogue: score[m] = sum_o tanh(out[m][o]) * wm[o]; direct + transpose ----
  float wmv[4];
#pragma unroll
  for (int nt = 0; nt < 4; ++nt) wmv[nt] = wm[nt*16 + colr];

#pragma unroll
  for (int a = 0; a < 2; ++a){
    float sacc[4] = {0.f,0.f,0.f,0.f};
#pragma unroll
    for (int nt = 0; nt < 4; ++nt){
#pragma unroll
      for (int r = 0; r < 4; ++r)
        sacc[r] += fast_tanh(acc[a][nt][r]) * wmv[nt];
    }
#pragma unroll
    for (int off = 1; off < 16; off <<= 1){
#pragma unroll
      for (int r = 0; r < 4; ++r) sacc[r] += __shfl_xor(sacc[r], off, 64);
    }
    if (colr == 0){
      int mb   = m0 + a*16 + grp*4;
      int base = (bb*NSEQ + n)*NSEQ + mb;
      float4 v = { sacc[0], sacc[1], sacc[2], sacc[3] };
      *(float4*)&scores[base] = v;
      if (wave > sn){             // diagonal strip covered by direct writes
        int tb = bb*NSEQ*NSEQ + n;
#pragma unroll
        for (int r = 0; r < 4; ++r)
          scores[tb + (mb + r)*NSEQ] = sacc[r];
      }
    }
  }
}

// ---------- kernel C: softmax + h_att + final KANs + BN, 4 rows/block ----------
// 256 blocks x 512 thr (8 waves). Softmax/h_att: 2 waves per row (rw=wave>>1).
// Weight stream (fragment-order S2) is swept in lockstep by all threads ->
// the shared 2KB chunk window is L1-hot; unique S2 traffic per block is
// amortized over 4 rows (75MB total vs R18's 151MB).
__launch_bounds__(512, 4)
__global__ void k_smf(const float* __restrict__ scores,
                      const float* __restrict__ h_ln,
                      const unsigned short* __restrict__ S2,
                      const float* __restrict__ bn_g, const float* __restrict__ bn_b,
                      const float* __restrict__ bn_mean, const float* __restrict__ bn_var,
                      float* __restrict__ out){
  __shared__ float att[4][256];
  __shared__ float redm[4][2], reds[4][2];
  __shared__ float part[4][2][64];
  __shared__ float hatt[4][64];
  __shared__ float feat[4][K2TOT];
  int row0 = blockIdx.x * 4;       // rows = b*256+n
  int tid = threadIdx.x, lane = tid & 63, wave = tid >> 6;  // 8 waves
  int rw = wave >> 1;              // row within block (0..3)
  int qw = wave & 1;               // wave within row (0/1)
  int row = row0 + rw;
  int t128 = (qw << 6) | lane;     // 0..127 within row

  // softmax over m (128 threads/row, 2 elems each)
  float s0 = scores[row*NSEQ + t128] * 0.125f;
  float s1 = scores[row*NSEQ + 128 + t128] * 0.125f;
  float mx = fmaxf(s0, s1);
#pragma unroll
  for (int off = 1; off < 64; off <<= 1) mx = fmaxf(mx, __shfl_xor(mx, off, 64));
  if (lane == 0) redm[rw][qw] = mx;
  __syncthreads();
  mx = fmaxf(redm[rw][0], redm[rw][1]);
  float e0 = __expf(s0 - mx), e1 = __expf(s1 - mx);
  float es = wave_sum(e0 + e1);
  if (lane == 0) reds[rw][qw] = es;
  __syncthreads();
  float tot = reds[rw][0] + reds[rw][1];
  att[rw][t128]       = e0 / tot;
  att[rw][128 + t128] = e1 / tot;
  __syncthreads();

  // h_att = attn @ h_ln (2 waves per row; 128 m each)
  int hb = row & ~255;             // b*256 (4 rows of a block share batch)
  float a2 = 0.f;
  for (int m = qw*128; m < qw*128 + 128; ++m)
    a2 += att[rw][m] * h_ln[(hb + m)*DIN + lane];
  part[rw][qw][lane] = a2;
  __syncthreads();
  if (qw == 0)
    hatt[rw][lane] = part[rw][0][lane] + part[rw][1][lane];
  __syncthreads();

  // feature build: 4 rows x 128 jobs = 512 jobs, 1 per thread
  {
    int rw2 = tid >> 7;            // 0..3
    int within = tid & 127;
    int src = within >> 6, dd = within & 63;
    float x = src ? h_ln[(row0 + rw2)*DIN + dd] : hatt[rw2][dd];
    x = fast_tanh(x);
    int base = src * KTOT;
    feat[rw2][base + dd] = silu_f(x);
    int fb = base + 64 + dd*8;
#pragma unroll
    for (int jj = 0; jj < 8; ++jj) feat[rw2][fb + jj] = 0.f;
    int i; float wgt[4];
    spline_w(x, i, wgt);
#pragma unroll
    for (int k = 0; k < 4; ++k){
      int jj = i + k;
      if (jj < 8) feat[rw2][fb + jj] = wgt[k];
    }
  }
  __syncthreads();

  // dot: thread (o = tid&127, g = tid>>7 in 0..3) over K=1152, fragment weights
  int o = tid & 127, g = tid >> 7;
  const unsigned short* sp = S2 + o*8;    // + jj*1024 per chunk
  const float* fp = feat[g];
  float acc = 0.f;
#pragma unroll 4
  for (int jj = 0; jj < K2TOT/8; ++jj){
    uint4  w  = *(const uint4*)(sp + jj*1024);
    float4 f0 = *(const float4*)(fp + jj*8);
    float4 f1 = *(const float4*)(fp + jj*8 + 4);
    acc = fmaf(f0.x, bf2f_lo(w.x), acc);
    acc = fmaf(f0.y, bf2f_hi(w.x), acc);
    acc = fmaf(f0.z, bf2f_lo(w.y), acc);
    acc = fmaf(f0.w, bf2f_hi(w.y), acc);
    acc = fmaf(f1.x, bf2f_lo(w.z), acc);
    acc = fmaf(f1.y, bf2f_hi(w.z), acc);
    acc = fmaf(f1.z, bf2f_lo(w.w), acc);
    acc = fmaf(f1.w, bf2f_hi(w.w), acc);
  }
  float r = (acc - bn_mean[o]) * rsqrtf(bn_var[o] + 1e-5f) * bn_g[o] + bn_b[o];
  out[(row0 + g)*DOUT + o] = r;
}

extern "C" void kernel_launch(void* const* d_in, const int* in_sizes, int n_in,
                              void* d_out, int out_size, void* d_ws, size_t ws_size,
                              hipStream_t stream){
  (void)in_sizes; (void)n_in; (void)out_size; (void)ws_size;
  const float* h       = (const float*)d_in[0];
  const float* ln_in_g = (const float*)d_in[1];
  const float* ln_in_b = (const float*)d_in[2];
  const float* ln_p_g  = (const float*)d_in[3];
  const float* ln_p_b  = (const float*)d_in[4];
  const float* ka_bw   = (const float*)d_in[5];
  const float* ka_sw   = (const float*)d_in[6];
  const float* ka_c    = (const float*)d_in[7];
  const float* W_att   = (const float*)d_in[8];
  const float* kp_bw   = (const float*)d_in[9];
  const float* kp_sw   = (const float*)d_in[10];
  const float* kp_c    = (const float*)d_in[11];
  const float* kd_bw   = (const float*)d_in[12];
  const float* kd_sw   = (const float*)d_in[13];
  const float* kd_c    = (const float*)d_in[14];
  const float* bn_g    = (const float*)d_in[15];
  const float* bn_b    = (const float*)d_in[16];
  const float* bn_mean = (const float*)d_in[17];
  const float* bn_var  = (const float*)d_in[18];
  float* out = (float*)d_out;

  char* ws = (char*)d_ws;
  float*          h_ln   = (float*)(ws + 0);                        // 256 KB
  float*          hn     = (float*)(ws + 262144);                   // 256 KB
  unsigned short* S_t    = (unsigned short*)(ws + 524288);          // 72 KB (fragment order)
  float*          wm     = (float*)(ws + 598016);                   // 256 B
  float*          scores = (float*)(ws + 598272);                   // 1 MB
  unsigned short* S2     = (unsigned short*)(ws + 1908992);         // 288 KB (fragment order)

  k_prep_all<<<449, 256, 0, stream>>>(h, ln_in_g, ln_in_b, ka_bw, ka_sw, ka_c, W_att,
                                      kp_bw, kp_sw, kp_c, kd_bw, kd_sw, kd_c,
                                      h_ln, hn, S_t, wm, S2);
  k_scores<<<1024, 512, 0, stream>>>(hn, ln_p_g, ln_p_b, S_t, wm, scores);
  k_smf<<<256, 512, 0, stream>>>(scores, h_ln, S2, bn_g, bn_b, bn_mean, bn_var, out);
}

// Round 20
// 76.632 us; speedup vs baseline: 1.0236x; 1.0236x over previous
//
#include <hip/hip_runtime.h>
#include <hip/hip_bf16.h>
#include <stdint.h>

// ---- problem constants ----
#define BBATCH 4
#define NSEQ   256
#define DIN    64
#define DOUT   128
#define NBASIS 8
#define KTOT   576   // 64 base (silu) + 64*8 spline features
#define K2TOT  1152  // two KANs worth of features for the final stage
#define NSTEP  18    // 576/32
#define XST16  68    // u16 stride for bf16 X rows
#define NJOBS  1152  // valid (n, m-strip) pairs per batch

typedef __attribute__((ext_vector_type(8))) __bf16 bf16x8;
typedef __attribute__((ext_vector_type(4))) float  f32x4;

__device__ __forceinline__ float wave_sum(float v){
#pragma unroll
  for (int m = 1; m < 64; m <<= 1) v += __shfl_xor(v, m, 64);
  return v;
}

__device__ __forceinline__ float fast_tanh(float y){
  y = fminf(10.f, fmaxf(-10.f, y));
  float e = __expf(2.f * y);
  return (e - 1.f) / (e + 1.f);
}

__device__ __forceinline__ float silu_f(float x){
  return __fdividef(x, 1.f + __expf(-x));
}

__device__ __forceinline__ unsigned short f2bf(float f){
  union { float f; unsigned u; } v; v.f = f;
  unsigned r = (v.u + 0x7fffu + ((v.u >> 16) & 1u)) >> 16;
  return (unsigned short)r;
}

__device__ __forceinline__ float bf2f(unsigned short s){
  union { unsigned u; float f; } v; v.u = ((unsigned)s) << 16;
  return v.f;
}

__device__ __forceinline__ float bf2f_lo(unsigned w){
  union { unsigned u; float f; } v; v.u = w << 16;
  return v.f;
}
__device__ __forceinline__ float bf2f_hi(unsigned w){
  union { unsigned u; float f; } v; v.u = w & 0xffff0000u;
  return v.f;
}

// pack two f32 -> one u32 of 2 bf16 (round-half-up) via v_perm_b32
__device__ __forceinline__ unsigned pk2(float a, float b){
  union { float f; unsigned u; } ua, ub; ua.f = a; ub.f = b;
  return __builtin_amdgcn_perm(ub.u + 0x8000u, ua.u + 0x8000u, 0x07060302);
}

// uniform cubic B-spline: grid [-1,1] step h=0.4, extended by 3 knots each side.
__device__ __forceinline__ void spline_w(float x, int &i, float w[4]){
  float u = (x + 1.f) * 2.5f;
  int ii = (int)floorf(u);
  ii = ii < 0 ? 0 : (ii > 5 ? 5 : ii);
  float t = u - (float)ii;
  float t2 = t * t, t3 = t2 * t;
  float it = 1.f - t;
  w[0] = it * it * it * (1.f/6.f);
  w[1] = (3.f*t3 - 6.f*t2 + 4.f) * (1.f/6.f);
  w[2] = (-3.f*t3 + 3.f*t2 + 3.f*t + 1.f) * (1.f/6.f);
  w[3] = t3 * (1.f/6.f);
  i = ii;
}

// full 8-slot packed spline basis row (bf16x8) for one x, in-register.
__device__ __forceinline__ bf16x8 spline_pack(float x){
  float u = (x + 1.f) * 2.5f;
  int ii = (int)floorf(u);
  ii = ii < 0 ? 0 : (ii > 5 ? 5 : ii);
  float t = u - (float)ii;
  float t2 = t * t, t3 = t2 * t;
  float it = 1.f - t;
  float w0 = it * it * it * (1.f/6.f);
  float w1 = (3.f*t3 - 6.f*t2 + 4.f) * (1.f/6.f);
  float w2 = (-3.f*t3 + 3.f*t2 + 3.f*t + 1.f) * (1.f/6.f);
  float w3 = t3 * (1.f/6.f);
  unsigned long long W = ((unsigned long long)pk2(w2, w3) << 32) | (unsigned long long)pk2(w0, w1);
  int s16 = ii << 4;
  unsigned long long shl_lo = W << (s16 & 63);
  unsigned long long shr    = W >> ((64 - s16) & 63);
  unsigned long long shl_hi = W << ((s16 - 64) & 63);
  bool ge4 = ii >= 4;
  unsigned long long lo = ge4 ? 0ull : shl_lo;
  unsigned long long hi = ge4 ? shl_hi : (ii == 0 ? 0ull : shr);
  union { unsigned long long q[2]; bf16x8 v8; } r;
  r.q[0] = lo; r.q[1] = hi;
  return r.v8;
}

// ---------- kernel A: fused prep (rows + S + wm + S2 + job table) ----------
// S_t in MFMA-fragment order (R17 win); S2 fragment order (R18 win).
// jobs[f] = (n<<3)|w for the f-th valid (n, m-strip) pair (w >= n>>5):
// uniform wave-jobs so k_scores blocks are perfectly load-balanced.
__global__ void k_prep_all(const float* __restrict__ h,
                           const float* __restrict__ g_in, const float* __restrict__ b_in,
                           const float* __restrict__ ka_bw, const float* __restrict__ ka_sw,
                           const float* __restrict__ ka_c,  const float* __restrict__ W_att,
                           const float* __restrict__ kp_bw, const float* __restrict__ kp_sw,
                           const float* __restrict__ kp_c,
                           const float* __restrict__ kd_bw, const float* __restrict__ kd_sw,
                           const float* __restrict__ kd_c,
                           float* __restrict__ h_ln, float* __restrict__ hn,
                           unsigned short* __restrict__ S_t, float* __restrict__ wm,
                           unsigned short* __restrict__ S2,
                           unsigned short* __restrict__ jobs){
  int blk = blockIdx.x, tid = threadIdx.x;
  if (blk < 256){                       // LN(h) + unit-norm: 4 rows/block
    int row = blk*4 + (tid >> 6);
    int d   = tid & 63;
    float x = h[row*DIN + d];
    float mean = wave_sum(x) * (1.f/64.f);
    float xm = x - mean;
    float var = wave_sum(xm*xm) * (1.f/64.f);
    float hl = xm * rsqrtf(var + 1e-5f) * g_in[d] + b_in[d];
    h_ln[row*DIN + d] = hl;
    float nrm = sqrtf(wave_sum(hl*hl));
    nrm = fmaxf(nrm, 1e-12f);
    hn[row*DIN + d] = hl / nrm;
  } else if (blk < 320){                // S_t in fragment order
    int o = blk - 256;
    int nt = o >> 4, colr = o & 15;
    for (int k = tid; k < KTOT; k += 256){
      float v;
      if (k < 64){
        v = ka_bw[o*64 + k];
      } else {
        int km = k - 64, dd = km >> 3, j = km & 7;
        float c = ka_c[(o*64 + dd)*8 + j];
        c = fminf(5.f, fmaxf(-5.f, c));
        v = c * ka_sw[o*64 + dd];
      }
      int s = k >> 5, grp = (k >> 3) & 3, e = k & 7;
      int lane = grp*16 + colr;
      S_t[((s*4 + nt)*64 + lane)*8 + e] = f2bf(v);
    }
  } else if (blk == 320){               // wm + job table
    if (tid < 64){
      float s = 0.f;
      for (int k = 0; k < 256; ++k) s += W_att[tid*256 + k];
      wm[tid] = s * (1.f/256.f);
    }
    const int offs[9] = {0,256,480,672,832,960,1056,1120,1152};
    for (int f = tid; f < NJOBS; f += 256){
      int t = 0;
      while (f >= offs[t+1]) ++t;       // n-tile 0..7
      int r = f - offs[t];
      int n = t*32 + r / (8 - t);
      int w = t + r % (8 - t);
      jobs[f] = (unsigned short)((n << 3) | w);
    }
  } else {                              // S2 fragment order
    int o = blk - 321;
    for (int kk = tid; kk < K2TOT; kk += 256){
      const float* bw; const float* sw; const float* cc;
      int k = kk;
      if (kk < KTOT){ bw = kp_bw; sw = kp_sw; cc = kp_c; }
      else          { bw = kd_bw; sw = kd_sw; cc = kd_c; k = kk - KTOT; }
      float v;
      if (k < 64){
        v = bw[o*64 + k];
      } else {
        int km = k - 64, d = km >> 3, j = km & 7;
        float c = cc[(o*64 + d)*8 + j];
        c = fminf(5.f, fmaxf(-5.f, c));
        v = c * sw[o*64 + d];
      }
      S2[((kk >> 3)*128 + o)*8 + (kk & 7)] = f2bf(v);
    }
  }
}

// ---------- kernel B: scores[b,n,m] — uniform wave-jobs, zero barriers ----------
// Grid 576 = 4 batches x 144 blocks; block = 8 uniform wave-jobs from the
// table. Every wave does identical work (32 rows x 18 K-steps) -> perfect
// balance, all blocks resident (2.25 blocks/CU). Everything wave-private:
// per-wave hnn strip, redundant g/b writes (benign same-value), no barriers.
// Per-wave math byte-identical to R18 -> bitwise-same scores.
__launch_bounds__(512, 4)
__global__ void k_scores(const float* __restrict__ hn,
                         const float* __restrict__ ln_p_g, const float* __restrict__ ln_p_b,
                         const unsigned short* __restrict__ S_t,
                         const float* __restrict__ wm,
                         const unsigned short* __restrict__ jobs,
                         float* __restrict__ scores){
  __shared__ unsigned short Xs[NSEQ * XST16];   // 8 strips x 32 rows = 34816 B
  __shared__ float hnn_l[8][64];
  __shared__ float g_l[64], b_l[64];

  int blkid = blockIdx.x;
  int bb    = blkid / 144;
  int jb    = (blkid % 144) * 8;

  int tid  = threadIdx.x;
  int lane = tid & 63, wave = tid >> 6;   // 8 waves, all active
  int job  = jobs[jb + wave];
  int n    = job >> 3;
  int w    = job & 7;
  int sn   = n >> 5;
  int m0g  = w * 32;               // global m-strip base
  int lr0  = wave * 32;            // LDS strip base

  // ---- per-wave broadcast data (redundant same-value writes for g/b) ----
  g_l[lane] = ln_p_g[lane];
  b_l[lane] = ln_p_b[lane];
  hnn_l[wave][lane] = bf2f(f2bf(hn[(bb*NSEQ + n)*DIN + lane]));  // bf16-rounded: bitwise symmetry

  // ---- phase 0: coalesced staging of this wave's 32 hn rows as bf16 ----
  {
    const float* src = hn + (bb*NSEQ + m0g)*DIN;
#pragma unroll
    for (int j = 0; j < 8; ++j){
      int f4 = j*64 + lane;                 // float4 index in wave's 2048 floats
      float4 v = *(const float4*)(src + f4*4);
      int r = f4 >> 4, c = (f4 & 15) * 4;
      uint2 pk = { pk2(v.x, v.y), pk2(v.z, v.w) };
      *(uint2*)(Xs + (lr0 + r)*XST16 + c) = pk;
    }
  }
  // same-wave LDS write->read ordering via lgkmcnt; no __syncthreads anywhere.

  // ---- phase 1: per-thread LN + tanh, in place (2 lanes/row, own strip) ----
  {
    int r = lane >> 1, hh = lane & 1;       // r in [0,32) within strip
    unsigned short* row = Xs + (lr0 + r)*XST16 + hh*32;
    const float* hp = hnn_l[wave] + hh*32;
    float s1 = 0.f, s2 = 0.f;
#pragma unroll
    for (int i = 0; i < 8; ++i){
      uint2 ww = *(const uint2*)(row + i*4);
      float x0 = bf2f_lo(ww.x), x1 = bf2f_hi(ww.x), x2 = bf2f_lo(ww.y), x3 = bf2f_hi(ww.y);
      float p0 = x0*hp[i*4+0], p1 = x1*hp[i*4+1], p2 = x2*hp[i*4+2], p3 = x3*hp[i*4+3];
      s1 += (p0+p1) + (p2+p3);
      s2 = fmaf(p0,p0, fmaf(p1,p1, fmaf(p2,p2, fmaf(p3,p3, s2))));
    }
    s1 += __shfl_xor(s1, 1, 64);
    s2 += __shfl_xor(s2, 1, 64);
    float mean = s1 * (1.f/64.f);
    float var  = fmaxf(s2 * (1.f/64.f) - mean*mean, 0.f);
    float inv  = rsqrtf(var + 1e-5f);
    const float* gp = g_l + hh*32;
    const float* bp = b_l + hh*32;
#pragma unroll
    for (int i = 0; i < 8; ++i){
      uint2 ww = *(const uint2*)(row + i*4);
      float x0 = bf2f_lo(ww.x), x1 = bf2f_hi(ww.x), x2 = bf2f_lo(ww.y), x3 = bf2f_hi(ww.y);
      float t0 = fast_tanh((x0*hp[i*4+0] - mean)*inv*gp[i*4+0] + bp[i*4+0]);
      float t1 = fast_tanh((x1*hp[i*4+1] - mean)*inv*gp[i*4+1] + bp[i*4+1]);
      float t2 = fast_tanh((x2*hp[i*4+2] - mean)*inv*gp[i*4+2] + bp[i*4+2]);
      float t3 = fast_tanh((x3*hp[i*4+3] - mean)*inv*gp[i*4+3] + bp[i*4+3]);
      uint2 pk = { pk2(t0, t1), pk2(t2, t3) };
      *(uint2*)(row + i*4) = pk;
    }
  }

  // ---- phase 2: MFMA K-loop, fragment-order B from global ----
  int colr = lane & 15, grp = lane >> 4;
  const unsigned short* rowA = Xs + (lr0 + colr)*XST16;
  const unsigned short* rowB = Xs + (lr0 + 16 + colr)*XST16;
  const unsigned short* sfp  = S_t + lane*8;   // + (s*4+nt)*512 per fragment

  f32x4 acc[2][4];
#pragma unroll
  for (int a = 0; a < 2; ++a)
#pragma unroll
    for (int c = 0; c < 4; ++c){ f32x4 z = {0.f,0.f,0.f,0.f}; acc[a][c] = z; }

  // silu steps (k = 0..63): lane's 8 k-slots = 8 dims
#pragma unroll
  for (int s = 0; s < 2; ++s){
    int kw = s*32 + grp*8;
    bf16x8 bf[4];
#pragma unroll
    for (int nt = 0; nt < 4; ++nt)
      bf[nt] = *(const bf16x8*)(sfp + (s*4 + nt)*512);
    union { unsigned u[4]; bf16x8 v8; } a0, a1;
    uint2 wa0 = *(const uint2*)(rowA + kw), wa1 = *(const uint2*)(rowA + kw + 4);
    uint2 wb0 = *(const uint2*)(rowB + kw), wb1 = *(const uint2*)(rowB + kw + 4);
    a0.u[0] = pk2(silu_f(bf2f_lo(wa0.x)), silu_f(bf2f_hi(wa0.x)));
    a0.u[1] = pk2(silu_f(bf2f_lo(wa0.y)), silu_f(bf2f_hi(wa0.y)));
    a0.u[2] = pk2(silu_f(bf2f_lo(wa1.x)), silu_f(bf2f_hi(wa1.x)));
    a0.u[3] = pk2(silu_f(bf2f_lo(wa1.y)), silu_f(bf2f_hi(wa1.y)));
    a1.u[0] = pk2(silu_f(bf2f_lo(wb0.x)), silu_f(bf2f_hi(wb0.x)));
    a1.u[1] = pk2(silu_f(bf2f_lo(wb0.y)), silu_f(bf2f_hi(wb0.y)));
    a1.u[2] = pk2(silu_f(bf2f_lo(wb1.x)), silu_f(bf2f_hi(wb1.x)));
    a1.u[3] = pk2(silu_f(bf2f_lo(wb1.y)), silu_f(bf2f_hi(wb1.y)));
#pragma unroll
    for (int nt = 0; nt < 4; ++nt){
      acc[0][nt] = __builtin_amdgcn_mfma_f32_16x16x32_bf16(a0.v8, bf[nt], acc[0][nt], 0, 0, 0);
      acc[1][nt] = __builtin_amdgcn_mfma_f32_16x16x32_bf16(a1.v8, bf[nt], acc[1][nt], 0, 0, 0);
    }
  }

  // spline steps (k = 64..575): lane's 8 k-slots = one dim's 8 bases
#pragma unroll 4
  for (int s = 2; s < NSTEP; ++s){
    int d  = (s - 2)*4 + grp;
    bf16x8 bf[4];
#pragma unroll
    for (int nt = 0; nt < 4; ++nt)
      bf[nt] = *(const bf16x8*)(sfp + (s*4 + nt)*512);
    bf16x8 a0 = spline_pack(bf2f(rowA[d]));
    bf16x8 a1 = spline_pack(bf2f(rowB[d]));
#pragma unroll
    for (int nt = 0; nt < 4; ++nt){
      acc[0][nt] = __builtin_amdgcn_mfma_f32_16x16x32_bf16(a0, bf[nt], acc[0][nt], 0, 0, 0);
      acc[1][nt] = __builtin_amdgcn_mfma_f32_16x16x32_bf16(a1, bf[nt], acc[1][nt], 0, 0, 0);
    }
  }

  // ---- epilogue: score[m] = sum_o tanh(out[m][o]) * wm[o]; direct + transpose ----
  float wmv[4];
#pragma unroll
  for (int nt = 0; nt < 4; ++nt) wmv[nt] = wm[nt*16 + colr];

#pragma unroll
  for (int a = 0; a < 2; ++a){
    float sacc[4] = {0.f,0.f,0.f,0.f};
#pragma unroll
    for (int nt = 0; nt < 4; ++nt){
#pragma unroll
      for (int r = 0; r < 4; ++r)
        sacc[r] += fast_tanh(acc[a][nt][r]) * wmv[nt];
    }
#pragma unroll
    for (int off = 1; off < 16; off <<= 1){
#pragma unroll
      for (int r = 0; r < 4; ++r) sacc[r] += __shfl_xor(sacc[r], off, 64);
    }
    if (colr == 0){
      int mb   = m0g + a*16 + grp*4;
      int base = (bb*NSEQ + n)*NSEQ + mb;
      float4 v = { sacc[0], sacc[1], sacc[2], sacc[3] };
      *(float4*)&scores[base] = v;
      if (w > sn){                // diagonal strip covered by direct writes
        int tb = bb*NSEQ*NSEQ + n;
#pragma unroll
        for (int r = 0; r < 4; ++r)
          scores[tb + (mb + r)*NSEQ] = sacc[r];
      }
    }
  }
}

// ---------- kernel C: softmax + h_att + final KANs + BN, 2 rows/block (R18) ----------
__launch_bounds__(256, 4)
__global__ void k_smf(const float* __restrict__ scores,
                      const float* __restrict__ h_ln,
                      const unsigned short* __restrict__ S2,
                      const float* __restrict__ bn_g, const float* __restrict__ bn_b,
                      const float* __restrict__ bn_mean, const float* __restrict__ bn_var,
                      float* __restrict__ out){
  __shared__ float att[2][256];
  __shared__ float redm[2][2], reds[2][2];
  __shared__ float part[2][2][64];
  __shared__ float hatt[2][64];
  __shared__ float feat[2][K2TOT];
  int row0 = blockIdx.x * 2;       // rows = b*256+n
  int tid = threadIdx.x, lane = tid & 63, wave = tid >> 6;  // 4 waves
  int rw = wave >> 1;              // row within block (0/1)
  int qw = wave & 1;               // wave within row (0/1)
  int row = row0 + rw;
  int t128 = (qw << 6) | lane;     // 0..127 within row

  // softmax over m (128 threads/row, 2 elems each)
  float s0 = scores[row*NSEQ + t128] * 0.125f;
  float s1 = scores[row*NSEQ + 128 + t128] * 0.125f;
  float mx = fmaxf(s0, s1);
#pragma unroll
  for (int off = 1; off < 64; off <<= 1) mx = fmaxf(mx, __shfl_xor(mx, off, 64));
  if (lane == 0) redm[rw][qw] = mx;
  __syncthreads();
  mx = fmaxf(redm[rw][0], redm[rw][1]);
  float e0 = __expf(s0 - mx), e1 = __expf(s1 - mx);
  float es = wave_sum(e0 + e1);
  if (lane == 0) reds[rw][qw] = es;
  __syncthreads();
  float tot = reds[rw][0] + reds[rw][1];
  att[rw][t128]       = e0 / tot;
  att[rw][128 + t128] = e1 / tot;
  __syncthreads();

  // h_att = attn @ h_ln (2 waves per row; 128 m each)
  int hb = row & ~255;             // b*256
  float a2 = 0.f;
  for (int m = qw*128; m < qw*128 + 128; ++m)
    a2 += att[rw][m] * h_ln[(hb + m)*DIN + lane];
  part[rw][qw][lane] = a2;
  __syncthreads();
  if (qw == 0)
    hatt[rw][lane] = part[rw][0][lane] + part[rw][1][lane];
  __syncthreads();

  // feature build: feat[rw][0:576) from tanh(h_att), [576:1152) from tanh(h_ln)
  {
    int src = t128 >> 6, dd = t128 & 63;
    float x = src ? h_ln[row*DIN + dd] : hatt[rw][dd];
    x = fast_tanh(x);
    int base = src * KTOT;
    feat[rw][base + dd] = silu_f(x);
    int fb = base + 64 + dd*8;
#pragma unroll
    for (int jj = 0; jj < 8; ++jj) feat[rw][fb + jj] = 0.f;
    int i; float wgt[4];
    spline_w(x, i, wgt);
#pragma unroll
    for (int k = 0; k < 4; ++k){
      int jj = i + k;
      if (jj < 8) feat[rw][fb + jj] = wgt[k];
    }
  }
  __syncthreads();

  // dot: thread (o = t128, row rw) over full K=1152, fragment-order weights
  int o = t128;
  const unsigned short* sp = S2 + o*8;    // + jj*1024 per chunk
  const float* fp = feat[rw];
  float acc = 0.f;
#pragma unroll 4
  for (int jj = 0; jj < K2TOT/8; ++jj){
    uint4  w  = *(const uint4*)(sp + jj*1024);
    float4 f0 = *(const float4*)(fp + jj*8);
    float4 f1 = *(const float4*)(fp + jj*8 + 4);
    acc = fmaf(f0.x, bf2f_lo(w.x), acc);
    acc = fmaf(f0.y, bf2f_hi(w.x), acc);
    acc = fmaf(f0.z, bf2f_lo(w.y), acc);
    acc = fmaf(f0.w, bf2f_hi(w.y), acc);
    acc = fmaf(f1.x, bf2f_lo(w.z), acc);
    acc = fmaf(f1.y, bf2f_hi(w.z), acc);
    acc = fmaf(f1.z, bf2f_lo(w.w), acc);
    acc = fmaf(f1.w, bf2f_hi(w.w), acc);
  }
  float r = (acc - bn_mean[o]) * rsqrtf(bn_var[o] + 1e-5f) * bn_g[o] + bn_b[o];
  out[row*DOUT + o] = r;
}

extern "C" void kernel_launch(void* const* d_in, const int* in_sizes, int n_in,
                              void* d_out, int out_size, void* d_ws, size_t ws_size,
                              hipStream_t stream){
  (void)in_sizes; (void)n_in; (void)out_size; (void)ws_size;
  const float* h       = (const float*)d_in[0];
  const float* ln_in_g = (const float*)d_in[1];
  const float* ln_in_b = (const float*)d_in[2];
  const float* ln_p_g  = (const float*)d_in[3];
  const float* ln_p_b  = (const float*)d_in[4];
  const float* ka_bw   = (const float*)d_in[5];
  const float* ka_sw   = (const float*)d_in[6];
  const float* ka_c    = (const float*)d_in[7];
  const float* W_att   = (const float*)d_in[8];
  const float* kp_bw   = (const float*)d_in[9];
  const float* kp_sw   = (const float*)d_in[10];
  const float* kp_c    = (const float*)d_in[11];
  const float* kd_bw   = (const float*)d_in[12];
  const float* kd_sw   = (const float*)d_in[13];
  const float* kd_c    = (const float*)d_in[14];
  const float* bn_g    = (const float*)d_in[15];
  const float* bn_b    = (const float*)d_in[16];
  const float* bn_mean = (const float*)d_in[17];
  const float* bn_var  = (const float*)d_in[18];
  float* out = (float*)d_out;

  char* ws = (char*)d_ws;
  float*          h_ln   = (float*)(ws + 0);                        // 256 KB
  float*          hn     = (float*)(ws + 262144);                   // 256 KB
  unsigned short* S_t    = (unsigned short*)(ws + 524288);          // 72 KB (fragment order)
  float*          wm     = (float*)(ws + 598016);                   // 256 B
  float*          scores = (float*)(ws + 598272);                   // 1 MB
  unsigned short* jobs   = (unsigned short*)(ws + 1646848);         // 2.3 KB
  unsigned short* S2     = (unsigned short*)(ws + 1908992);         // 288 KB (fragment order)

  k_prep_all<<<449, 256, 0, stream>>>(h, ln_in_g, ln_in_b, ka_bw, ka_sw, ka_c, W_att,
                                      kp_bw, kp_sw, kp_c, kd_bw, kd_sw, kd_c,
                                      h_ln, hn, S_t, wm, S2, jobs);
  k_scores<<<576, 512, 0, stream>>>(hn, ln_p_g, ln_p_b, S_t, wm, jobs, scores);
  k_smf<<<512, 256, 0, stream>>>(scores, h_ln, S2, bn_g, bn_b, bn_mean, bn_var, out);
}

// Round 21
// 64.456 us; speedup vs baseline: 1.2170x; 1.1889x over previous
//
#include <hip/hip_runtime.h>
#include <hip/hip_bf16.h>
#include <stdint.h>

// ---- problem constants ----
#define BBATCH 4
#define NSEQ   256
#define DIN    64
#define DOUT   128
#define NBASIS 8
#define KTOT   576   // 64 base (silu) + 64*8 spline features
#define K2TOT  1152  // two KANs worth of features for the final stage
#define NSTEP  18    // 576/32
#define XST16  68    // u16 stride for bf16 X rows
#define NJOBS  1152  // valid (n, m-strip) pairs per batch

typedef __attribute__((ext_vector_type(8))) __bf16 bf16x8;
typedef __attribute__((ext_vector_type(4))) float  f32x4;

__device__ __forceinline__ float wave_sum(float v){
#pragma unroll
  for (int m = 1; m < 64; m <<= 1) v += __shfl_xor(v, m, 64);
  return v;
}

__device__ __forceinline__ float fast_tanh(float y){
  y = fminf(10.f, fmaxf(-10.f, y));
  float e = __expf(2.f * y);
  return (e - 1.f) / (e + 1.f);
}

__device__ __forceinline__ float silu_f(float x){
  return __fdividef(x, 1.f + __expf(-x));
}

__device__ __forceinline__ unsigned short f2bf(float f){
  union { float f; unsigned u; } v; v.f = f;
  unsigned r = (v.u + 0x7fffu + ((v.u >> 16) & 1u)) >> 16;
  return (unsigned short)r;
}

__device__ __forceinline__ float bf2f(unsigned short s){
  union { unsigned u; float f; } v; v.u = ((unsigned)s) << 16;
  return v.f;
}

__device__ __forceinline__ float bf2f_lo(unsigned w){
  union { unsigned u; float f; } v; v.u = w << 16;
  return v.f;
}
__device__ __forceinline__ float bf2f_hi(unsigned w){
  union { unsigned u; float f; } v; v.u = w & 0xffff0000u;
  return v.f;
}

// pack two f32 -> one u32 of 2 bf16 (round-half-up) via v_perm_b32
__device__ __forceinline__ unsigned pk2(float a, float b){
  union { float f; unsigned u; } ua, ub; ua.f = a; ub.f = b;
  return __builtin_amdgcn_perm(ub.u + 0x8000u, ua.u + 0x8000u, 0x07060302);
}

// uniform cubic B-spline: grid [-1,1] step h=0.4, extended by 3 knots each side.
__device__ __forceinline__ void spline_w(float x, int &i, float w[4]){
  float u = (x + 1.f) * 2.5f;
  int ii = (int)floorf(u);
  ii = ii < 0 ? 0 : (ii > 5 ? 5 : ii);
  float t = u - (float)ii;
  float t2 = t * t, t3 = t2 * t;
  float it = 1.f - t;
  w[0] = it * it * it * (1.f/6.f);
  w[1] = (3.f*t3 - 6.f*t2 + 4.f) * (1.f/6.f);
  w[2] = (-3.f*t3 + 3.f*t2 + 3.f*t + 1.f) * (1.f/6.f);
  w[3] = t3 * (1.f/6.f);
  i = ii;
}

// full 8-slot packed spline basis row (bf16x8) for one x, in-register.
__device__ __forceinline__ bf16x8 spline_pack(float x){
  float u = (x + 1.f) * 2.5f;
  int ii = (int)floorf(u);
  ii = ii < 0 ? 0 : (ii > 5 ? 5 : ii);
  float t = u - (float)ii;
  float t2 = t * t, t3 = t2 * t;
  float it = 1.f - t;
  float w0 = it * it * it * (1.f/6.f);
  float w1 = (3.f*t3 - 6.f*t2 + 4.f) * (1.f/6.f);
  float w2 = (-3.f*t3 + 3.f*t2 + 3.f*t + 1.f) * (1.f/6.f);
  float w3 = t3 * (1.f/6.f);
  unsigned long long W = ((unsigned long long)pk2(w2, w3) << 32) | (unsigned long long)pk2(w0, w1);
  int s16 = ii << 4;
  unsigned long long shl_lo = W << (s16 & 63);
  unsigned long long shr    = W >> ((64 - s16) & 63);
  unsigned long long shl_hi = W << ((s16 - 64) & 63);
  bool ge4 = ii >= 4;
  unsigned long long lo = ge4 ? 0ull : shl_lo;
  unsigned long long hi = ge4 ? shl_hi : (ii == 0 ? 0ull : shr);
  union { unsigned long long q[2]; bf16x8 v8; } r;
  r.q[0] = lo; r.q[1] = hi;
  return r.v8;
}

// ---------- kernel A: fused prep (rows + S + wm + S2 + job table) ----------
__global__ void k_prep_all(const float* __restrict__ h,
                           const float* __restrict__ g_in, const float* __restrict__ b_in,
                           const float* __restrict__ ka_bw, const float* __restrict__ ka_sw,
                           const float* __restrict__ ka_c,  const float* __restrict__ W_att,
                           const float* __restrict__ kp_bw, const float* __restrict__ kp_sw,
                           const float* __restrict__ kp_c,
                           const float* __restrict__ kd_bw, const float* __restrict__ kd_sw,
                           const float* __restrict__ kd_c,
                           float* __restrict__ h_ln, float* __restrict__ hn,
                           unsigned short* __restrict__ S_t, float* __restrict__ wm,
                           unsigned short* __restrict__ S2,
                           unsigned short* __restrict__ jobs){
  int blk = blockIdx.x, tid = threadIdx.x;
  if (blk < 256){                       // LN(h) + unit-norm: 4 rows/block
    int row = blk*4 + (tid >> 6);
    int d   = tid & 63;
    float x = h[row*DIN + d];
    float mean = wave_sum(x) * (1.f/64.f);
    float xm = x - mean;
    float var = wave_sum(xm*xm) * (1.f/64.f);
    float hl = xm * rsqrtf(var + 1e-5f) * g_in[d] + b_in[d];
    h_ln[row*DIN + d] = hl;
    float nrm = sqrtf(wave_sum(hl*hl));
    nrm = fmaxf(nrm, 1e-12f);
    hn[row*DIN + d] = hl / nrm;
  } else if (blk < 320){                // S_t in fragment order (R17 win)
    int o = blk - 256;
    int nt = o >> 4, colr = o & 15;
    for (int k = tid; k < KTOT; k += 256){
      float v;
      if (k < 64){
        v = ka_bw[o*64 + k];
      } else {
        int km = k - 64, dd = km >> 3, j = km & 7;
        float c = ka_c[(o*64 + dd)*8 + j];
        c = fminf(5.f, fmaxf(-5.f, c));
        v = c * ka_sw[o*64 + dd];
      }
      int s = k >> 5, grp = (k >> 3) & 3, e = k & 7;
      int lane = grp*16 + colr;
      S_t[((s*4 + nt)*64 + lane)*8 + e] = f2bf(v);
    }
  } else if (blk == 320){               // wm + job table
    if (tid < 64){
      float s = 0.f;
      for (int k = 0; k < 256; ++k) s += W_att[tid*256 + k];
      wm[tid] = s * (1.f/256.f);
    }
    const int offs[9] = {0,256,480,672,832,960,1056,1120,1152};
    for (int f = tid; f < NJOBS; f += 256){
      int t = 0;
      while (f >= offs[t+1]) ++t;       // n-tile 0..7
      int r = f - offs[t];
      int n = t*32 + r / (8 - t);
      int w = t + r % (8 - t);
      jobs[f] = (unsigned short)((n << 3) | w);
    }
  } else {                              // S2 fragment order (R18 win)
    int o = blk - 321;
    for (int kk = tid; kk < K2TOT; kk += 256){
      const float* bw; const float* sw; const float* cc;
      int k = kk;
      if (kk < KTOT){ bw = kp_bw; sw = kp_sw; cc = kp_c; }
      else          { bw = kd_bw; sw = kd_sw; cc = kd_c; k = kk - KTOT; }
      float v;
      if (k < 64){
        v = bw[o*64 + k];
      } else {
        int km = k - 64, d = km >> 3, j = km & 7;
        float c = cc[(o*64 + d)*8 + j];
        c = fminf(5.f, fmaxf(-5.f, c));
        v = c * sw[o*64 + d];
      }
      S2[((kk >> 3)*128 + o)*8 + (kk & 7)] = f2bf(v);
    }
  }
}

// ---------- kernel B: scores[b,n,m] — uniform wave-jobs, 4-wave blocks ----------
// Grid 1152 = 4 batches x 288 blocks; block = 4 uniform wave-jobs (4.5
// blocks/CU -> smaller dispatch tail than R20's 2.25). Everything
// wave-private, zero barriers; per-wave math byte-identical to R20.
__launch_bounds__(256, 4)
__global__ void k_scores(const float* __restrict__ hn,
                         const float* __restrict__ ln_p_g, const float* __restrict__ ln_p_b,
                         const unsigned short* __restrict__ S_t,
                         const float* __restrict__ wm,
                         const unsigned short* __restrict__ jobs,
                         float* __restrict__ scores){
  __shared__ unsigned short Xs[128 * XST16];   // 4 strips x 32 rows = 17408 B
  __shared__ float hnn_l[4][64];
  __shared__ float g_l[64], b_l[64];

  int blkid = blockIdx.x;
  int bb    = blkid / 288;
  int jb    = (blkid % 288) * 4;

  int tid  = threadIdx.x;
  int lane = tid & 63, wave = tid >> 6;   // 4 waves, all active
  int job  = jobs[jb + wave];
  int n    = job >> 3;
  int w    = job & 7;
  int sn   = n >> 5;
  int m0g  = w * 32;               // global m-strip base
  int lr0  = wave * 32;            // LDS strip base

  // ---- per-wave broadcast data (redundant same-value writes for g/b) ----
  g_l[lane] = ln_p_g[lane];
  b_l[lane] = ln_p_b[lane];
  hnn_l[wave][lane] = bf2f(f2bf(hn[(bb*NSEQ + n)*DIN + lane]));  // bf16-rounded: bitwise symmetry

  // ---- phase 0: coalesced staging of this wave's 32 hn rows as bf16 ----
  {
    const float* src = hn + (bb*NSEQ + m0g)*DIN;
#pragma unroll
    for (int j = 0; j < 8; ++j){
      int f4 = j*64 + lane;                 // float4 index in wave's 2048 floats
      float4 v = *(const float4*)(src + f4*4);
      int r = f4 >> 4, c = (f4 & 15) * 4;
      uint2 pk = { pk2(v.x, v.y), pk2(v.z, v.w) };
      *(uint2*)(Xs + (lr0 + r)*XST16 + c) = pk;
    }
  }
  // same-wave LDS write->read ordering via lgkmcnt; no __syncthreads anywhere.

  // ---- phase 1: per-thread LN + tanh, in place (2 lanes/row, own strip) ----
  {
    int r = lane >> 1, hh = lane & 1;       // r in [0,32) within strip
    unsigned short* row = Xs + (lr0 + r)*XST16 + hh*32;
    const float* hp = hnn_l[wave] + hh*32;
    float s1 = 0.f, s2 = 0.f;
#pragma unroll
    for (int i = 0; i < 8; ++i){
      uint2 ww = *(const uint2*)(row + i*4);
      float x0 = bf2f_lo(ww.x), x1 = bf2f_hi(ww.x), x2 = bf2f_lo(ww.y), x3 = bf2f_hi(ww.y);
      float p0 = x0*hp[i*4+0], p1 = x1*hp[i*4+1], p2 = x2*hp[i*4+2], p3 = x3*hp[i*4+3];
      s1 += (p0+p1) + (p2+p3);
      s2 = fmaf(p0,p0, fmaf(p1,p1, fmaf(p2,p2, fmaf(p3,p3, s2))));
    }
    s1 += __shfl_xor(s1, 1, 64);
    s2 += __shfl_xor(s2, 1, 64);
    float mean = s1 * (1.f/64.f);
    float var  = fmaxf(s2 * (1.f/64.f) - mean*mean, 0.f);
    float inv  = rsqrtf(var + 1e-5f);
    const float* gp = g_l + hh*32;
    const float* bp = b_l + hh*32;
#pragma unroll
    for (int i = 0; i < 8; ++i){
      uint2 ww = *(const uint2*)(row + i*4);
      float x0 = bf2f_lo(ww.x), x1 = bf2f_hi(ww.x), x2 = bf2f_lo(ww.y), x3 = bf2f_hi(ww.y);
      float t0 = fast_tanh((x0*hp[i*4+0] - mean)*inv*gp[i*4+0] + bp[i*4+0]);
      float t1 = fast_tanh((x1*hp[i*4+1] - mean)*inv*gp[i*4+1] + bp[i*4+1]);
      float t2 = fast_tanh((x2*hp[i*4+2] - mean)*inv*gp[i*4+2] + bp[i*4+2]);
      float t3 = fast_tanh((x3*hp[i*4+3] - mean)*inv*gp[i*4+3] + bp[i*4+3]);
      uint2 pk = { pk2(t0, t1), pk2(t2, t3) };
      *(uint2*)(row + i*4) = pk;
    }
  }

  // ---- phase 2: MFMA K-loop, fragment-order B from global ----
  int colr = lane & 15, grp = lane >> 4;
  const unsigned short* rowA = Xs + (lr0 + colr)*XST16;
  const unsigned short* rowB = Xs + (lr0 + 16 + colr)*XST16;
  const unsigned short* sfp  = S_t + lane*8;   // + (s*4+nt)*512 per fragment

  f32x4 acc[2][4];
#pragma unroll
  for (int a = 0; a < 2; ++a)
#pragma unroll
    for (int c = 0; c < 4; ++c){ f32x4 z = {0.f,0.f,0.f,0.f}; acc[a][c] = z; }

  // silu steps (k = 0..63): lane's 8 k-slots = 8 dims
#pragma unroll
  for (int s = 0; s < 2; ++s){
    int kw = s*32 + grp*8;
    bf16x8 bf[4];
#pragma unroll
    for (int nt = 0; nt < 4; ++nt)
      bf[nt] = *(const bf16x8*)(sfp + (s*4 + nt)*512);
    union { unsigned u[4]; bf16x8 v8; } a0, a1;
    uint2 wa0 = *(const uint2*)(rowA + kw), wa1 = *(const uint2*)(rowA + kw + 4);
    uint2 wb0 = *(const uint2*)(rowB + kw), wb1 = *(const uint2*)(rowB + kw + 4);
    a0.u[0] = pk2(silu_f(bf2f_lo(wa0.x)), silu_f(bf2f_hi(wa0.x)));
    a0.u[1] = pk2(silu_f(bf2f_lo(wa0.y)), silu_f(bf2f_hi(wa0.y)));
    a0.u[2] = pk2(silu_f(bf2f_lo(wa1.x)), silu_f(bf2f_hi(wa1.x)));
    a0.u[3] = pk2(silu_f(bf2f_lo(wa1.y)), silu_f(bf2f_hi(wa1.y)));
    a1.u[0] = pk2(silu_f(bf2f_lo(wb0.x)), silu_f(bf2f_hi(wb0.x)));
    a1.u[1] = pk2(silu_f(bf2f_lo(wb0.y)), silu_f(bf2f_hi(wb0.y)));
    a1.u[2] = pk2(silu_f(bf2f_lo(wb1.x)), silu_f(bf2f_hi(wb1.x)));
    a1.u[3] = pk2(silu_f(bf2f_lo(wb1.y)), silu_f(bf2f_hi(wb1.y)));
#pragma unroll
    for (int nt = 0; nt < 4; ++nt){
      acc[0][nt] = __builtin_amdgcn_mfma_f32_16x16x32_bf16(a0.v8, bf[nt], acc[0][nt], 0, 0, 0);
      acc[1][nt] = __builtin_amdgcn_mfma_f32_16x16x32_bf16(a1.v8, bf[nt], acc[1][nt], 0, 0, 0);
    }
  }

  // spline steps (k = 64..575): lane's 8 k-slots = one dim's 8 bases
#pragma unroll 4
  for (int s = 2; s < NSTEP; ++s){
    int d  = (s - 2)*4 + grp;
    bf16x8 bf[4];
#pragma unroll
    for (int nt = 0; nt < 4; ++nt)
      bf[nt] = *(const bf16x8*)(sfp + (s*4 + nt)*512);
    bf16x8 a0 = spline_pack(bf2f(rowA[d]));
    bf16x8 a1 = spline_pack(bf2f(rowB[d]));
#pragma unroll
    for (int nt = 0; nt < 4; ++nt){
      acc[0][nt] = __builtin_amdgcn_mfma_f32_16x16x32_bf16(a0, bf[nt], acc[0][nt], 0, 0, 0);
      acc[1][nt] = __builtin_amdgcn_mfma_f32_16x16x32_bf16(a1, bf[nt], acc[1][nt], 0, 0, 0);
    }
  }

  // ---- epilogue: score[m] = sum_o tanh(out[m][o]) * wm[o]; direct + transpose ----
  float wmv[4];
#pragma unroll
  for (int nt = 0; nt < 4; ++nt) wmv[nt] = wm[nt*16 + colr];

#pragma unroll
  for (int a = 0; a < 2; ++a){
    float sacc[4] = {0.f,0.f,0.f,0.f};
#pragma unroll
    for (int nt = 0; nt < 4; ++nt){
#pragma unroll
      for (int r = 0; r < 4; ++r)
        sacc[r] += fast_tanh(acc[a][nt][r]) * wmv[nt];
    }
#pragma unroll
    for (int off = 1; off < 16; off <<= 1){
#pragma unroll
      for (int r = 0; r < 4; ++r) sacc[r] += __shfl_xor(sacc[r], off, 64);
    }
    if (colr == 0){
      int mb   = m0g + a*16 + grp*4;
      int base = (bb*NSEQ + n)*NSEQ + mb;
      float4 v = { sacc[0], sacc[1], sacc[2], sacc[3] };
      *(float4*)&scores[base] = v;
      if (w > sn){                // diagonal strip covered by direct writes
        int tb = bb*NSEQ*NSEQ + n;
#pragma unroll
        for (int r = 0; r < 4; ++r)
          scores[tb + (mb + r)*NSEQ] = sacc[r];
      }
    }
  }
}

// ---------- kernel C: softmax + h_att + final KANs + BN ----------
// 512 blocks x 512 thr; 2 rows/block, 4 waves per row. K-dot split over 2
// threads (72 chunks each) + LDS reduce: halves the serial load chain that
// made R18's k_smf latency-bound.
__launch_bounds__(512, 4)
__global__ void k_smf(const float* __restrict__ scores,
                      const float* __restrict__ h_ln,
                      const unsigned short* __restrict__ S2,
                      const float* __restrict__ bn_g, const float* __restrict__ bn_b,
                      const float* __restrict__ bn_mean, const float* __restrict__ bn_var,
                      float* __restrict__ out){
  __shared__ float att[2][256];
  __shared__ float redm[2][4], reds[2][4];
  __shared__ float part[2][4][64];
  __shared__ float hatt[2][64];
  __shared__ float feat[2][K2TOT];
  __shared__ float pout[2][128];
  int row0 = blockIdx.x * 2;       // rows = b*256+n
  int tid = threadIdx.x, lane = tid & 63;
  int rw   = tid >> 8;             // row within block (0/1)
  int wv4  = (tid >> 6) & 3;       // wave within row (0..3)
  int t256 = tid & 255;            // 0..255 within row
  int row  = row0 + rw;

  // softmax over m: 256 threads/row, 1 element each
  float sc = scores[row*NSEQ + t256] * 0.125f;
  float mx = sc;
#pragma unroll
  for (int off = 1; off < 64; off <<= 1) mx = fmaxf(mx, __shfl_xor(mx, off, 64));
  if (lane == 0) redm[rw][wv4] = mx;
  __syncthreads();
  mx = fmaxf(fmaxf(redm[rw][0], redm[rw][1]), fmaxf(redm[rw][2], redm[rw][3]));
  float e = __expf(sc - mx);
  float es = wave_sum(e);
  if (lane == 0) reds[rw][wv4] = es;
  __syncthreads();
  float tot = (reds[rw][0] + reds[rw][1]) + (reds[rw][2] + reds[rw][3]);
  att[rw][t256] = e / tot;
  __syncthreads();

  // h_att = attn @ h_ln (4 waves per row; 64 m each)
  int hb = row & ~255;             // b*256
  float a2 = 0.f;
  for (int m = wv4*64; m < wv4*64 + 64; ++m)
    a2 += att[rw][m] * h_ln[(hb + m)*DIN + lane];
  part[rw][wv4][lane] = a2;
  __syncthreads();
  if (wv4 == 0)
    hatt[rw][lane] = (part[rw][0][lane] + part[rw][1][lane])
                   + (part[rw][2][lane] + part[rw][3][lane]);
  __syncthreads();

  // feature build: 2 rows x 128 jobs; threads with t256<128 do them
  if (t256 < 128){
    int src = t256 >> 6, dd = t256 & 63;
    float x = src ? h_ln[row*DIN + dd] : hatt[rw][dd];
    x = fast_tanh(x);
    int base = src * KTOT;
    feat[rw][base + dd] = silu_f(x);
    int fb = base + 64 + dd*8;
#pragma unroll
    for (int jj = 0; jj < 8; ++jj) feat[rw][fb + jj] = 0.f;
    int i; float wgt[4];
    spline_w(x, i, wgt);
#pragma unroll
    for (int k = 0; k < 4; ++k){
      int jj = i + k;
      if (jj < 8) feat[rw][fb + jj] = wgt[k];
    }
  }
  __syncthreads();

  // dot: thread (rw, half = t256>>7, o = t256&127); 72 chunks each
  int o = t256 & 127, half = t256 >> 7;
  const unsigned short* sp = S2 + o*8 + half*72*1024;
  const float* fp = feat[rw] + half*576;
  float acc = 0.f;
#pragma unroll 4
  for (int jj = 0; jj < 72; ++jj){
    uint4  w  = *(const uint4*)(sp + jj*1024);
    float4 f0 = *(const float4*)(fp + jj*8);
    float4 f1 = *(const float4*)(fp + jj*8 + 4);
    acc = fmaf(f0.x, bf2f_lo(w.x), acc);
    acc = fmaf(f0.y, bf2f_hi(w.x), acc);
    acc = fmaf(f0.z, bf2f_lo(w.y), acc);
    acc = fmaf(f0.w, bf2f_hi(w.y), acc);
    acc = fmaf(f1.x, bf2f_lo(w.z), acc);
    acc = fmaf(f1.y, bf2f_hi(w.z), acc);
    acc = fmaf(f1.z, bf2f_lo(w.w), acc);
    acc = fmaf(f1.w, bf2f_hi(w.w), acc);
  }
  if (half) pout[rw][o] = acc;
  __syncthreads();
  if (!half){
    float a = acc + pout[rw][o];
    float r = (a - bn_mean[o]) * rsqrtf(bn_var[o] + 1e-5f) * bn_g[o] + bn_b[o];
    out[row*DOUT + o] = r;
  }
}

extern "C" void kernel_launch(void* const* d_in, const int* in_sizes, int n_in,
                              void* d_out, int out_size, void* d_ws, size_t ws_size,
                              hipStream_t stream){
  (void)in_sizes; (void)n_in; (void)out_size; (void)ws_size;
  const float* h       = (const float*)d_in[0];
  const float* ln_in_g = (const float*)d_in[1];
  const float* ln_in_b = (const float*)d_in[2];
  const float* ln_p_g  = (const float*)d_in[3];
  const float* ln_p_b  = (const float*)d_in[4];
  const float* ka_bw   = (const float*)d_in[5];
  const float* ka_sw   = (const float*)d_in[6];
  const float* ka_c    = (const float*)d_in[7];
  const float* W_att   = (const float*)d_in[8];
  const float* kp_bw   = (const float*)d_in[9];
  const float* kp_sw   = (const float*)d_in[10];
  const float* kp_c    = (const float*)d_in[11];
  const float* kd_bw   = (const float*)d_in[12];
  const float* kd_sw   = (const float*)d_in[13];
  const float* kd_c    = (const float*)d_in[14];
  const float* bn_g    = (const float*)d_in[15];
  const float* bn_b    = (const float*)d_in[16];
  const float* bn_mean = (const float*)d_in[17];
  const float* bn_var  = (const float*)d_in[18];
  float* out = (float*)d_out;

  char* ws = (char*)d_ws;
  float*          h_ln   = (float*)(ws + 0);                        // 256 KB
  float*          hn     = (float*)(ws + 262144);                   // 256 KB
  unsigned short* S_t    = (unsigned short*)(ws + 524288);          // 72 KB (fragment order)
  float*          wm     = (float*)(ws + 598016);                   // 256 B
  float*          scores = (float*)(ws + 598272);                   // 1 MB
  unsigned short* jobs   = (unsigned short*)(ws + 1646848);         // 2.3 KB
  unsigned short* S2     = (unsigned short*)(ws + 1908992);         // 288 KB (fragment order)

  k_prep_all<<<449, 256, 0, stream>>>(h, ln_in_g, ln_in_b, ka_bw, ka_sw, ka_c, W_att,
                                      kp_bw, kp_sw, kp_c, kd_bw, kd_sw, kd_c,
                                      h_ln, hn, S_t, wm, S2, jobs);
  k_scores<<<1152, 256, 0, stream>>>(hn, ln_p_g, ln_p_b, S_t, wm, jobs, scores);
  k_smf<<<512, 512, 0, stream>>>(scores, h_ln, S2, bn_g, bn_b, bn_mean, bn_var, out);
}

// Round 22
// 64.021 us; speedup vs baseline: 1.2253x; 1.0068x over previous
//
#include <hip/hip_runtime.h>
#include <hip/hip_bf16.h>
#include <stdint.h>

// ---- problem constants ----
#define BBATCH 4
#define NSEQ   256
#define DIN    64
#define DOUT   128
#define NBASIS 8
#define KTOT   576   // 64 base (silu) + 64*8 spline features
#define K2TOT  1152  // two KANs worth of features for the final stage
#define NSTEP  18    // 576/32
#define XST16  68    // u16 stride for bf16 X rows
#define NJOBS  1152  // valid (n, m-strip) pairs per batch

typedef __attribute__((ext_vector_type(8))) __bf16 bf16x8;
typedef __attribute__((ext_vector_type(4))) float  f32x4;

__device__ __forceinline__ float wave_sum(float v){
#pragma unroll
  for (int m = 1; m < 64; m <<= 1) v += __shfl_xor(v, m, 64);
  return v;
}

__device__ __forceinline__ float fast_tanh(float y){
  y = fminf(10.f, fmaxf(-10.f, y));
  float e = __expf(2.f * y);
  return (e - 1.f) / (e + 1.f);
}

__device__ __forceinline__ float silu_f(float x){
  return __fdividef(x, 1.f + __expf(-x));
}

__device__ __forceinline__ unsigned short f2bf(float f){
  union { float f; unsigned u; } v; v.f = f;
  unsigned r = (v.u + 0x7fffu + ((v.u >> 16) & 1u)) >> 16;
  return (unsigned short)r;
}

__device__ __forceinline__ float bf2f(unsigned short s){
  union { unsigned u; float f; } v; v.u = ((unsigned)s) << 16;
  return v.f;
}

__device__ __forceinline__ float bf2f_lo(unsigned w){
  union { unsigned u; float f; } v; v.u = w << 16;
  return v.f;
}
__device__ __forceinline__ float bf2f_hi(unsigned w){
  union { unsigned u; float f; } v; v.u = w & 0xffff0000u;
  return v.f;
}

// pack two f32 -> one u32 of 2 bf16 (round-half-up) via v_perm_b32
__device__ __forceinline__ unsigned pk2(float a, float b){
  union { float f; unsigned u; } ua, ub; ua.f = a; ub.f = b;
  return __builtin_amdgcn_perm(ub.u + 0x8000u, ua.u + 0x8000u, 0x07060302);
}

// uniform cubic B-spline: grid [-1,1] step h=0.4, extended by 3 knots each side.
__device__ __forceinline__ void spline_w(float x, int &i, float w[4]){
  float u = (x + 1.f) * 2.5f;
  int ii = (int)floorf(u);
  ii = ii < 0 ? 0 : (ii > 5 ? 5 : ii);
  float t = u - (float)ii;
  float t2 = t * t, t3 = t2 * t;
  float it = 1.f - t;
  w[0] = it * it * it * (1.f/6.f);
  w[1] = (3.f*t3 - 6.f*t2 + 4.f) * (1.f/6.f);
  w[2] = (-3.f*t3 + 3.f*t2 + 3.f*t + 1.f) * (1.f/6.f);
  w[3] = t3 * (1.f/6.f);
  i = ii;
}

// full 8-slot packed spline basis row (bf16x8) for one x, in-register.
__device__ __forceinline__ bf16x8 spline_pack(float x){
  float u = (x + 1.f) * 2.5f;
  int ii = (int)floorf(u);
  ii = ii < 0 ? 0 : (ii > 5 ? 5 : ii);
  float t = u - (float)ii;
  float t2 = t * t, t3 = t2 * t;
  float it = 1.f - t;
  float w0 = it * it * it * (1.f/6.f);
  float w1 = (3.f*t3 - 6.f*t2 + 4.f) * (1.f/6.f);
  float w2 = (-3.f*t3 + 3.f*t2 + 3.f*t + 1.f) * (1.f/6.f);
  float w3 = t3 * (1.f/6.f);
  unsigned long long W = ((unsigned long long)pk2(w2, w3) << 32) | (unsigned long long)pk2(w0, w1);
  int s16 = ii << 4;
  unsigned long long shl_lo = W << (s16 & 63);
  unsigned long long shr    = W >> ((64 - s16) & 63);
  unsigned long long shl_hi = W << ((s16 - 64) & 63);
  bool ge4 = ii >= 4;
  unsigned long long lo = ge4 ? 0ull : shl_lo;
  unsigned long long hi = ge4 ? shl_hi : (ii == 0 ? 0ull : shr);
  union { unsigned long long q[2]; bf16x8 v8; } r;
  r.q[0] = lo; r.q[1] = hi;
  return r.v8;
}

// ---------- kernel A: fused prep (rows + S + wm + S2 + job table) ----------
__global__ void k_prep_all(const float* __restrict__ h,
                           const float* __restrict__ g_in, const float* __restrict__ b_in,
                           const float* __restrict__ ka_bw, const float* __restrict__ ka_sw,
                           const float* __restrict__ ka_c,  const float* __restrict__ W_att,
                           const float* __restrict__ kp_bw, const float* __restrict__ kp_sw,
                           const float* __restrict__ kp_c,
                           const float* __restrict__ kd_bw, const float* __restrict__ kd_sw,
                           const float* __restrict__ kd_c,
                           float* __restrict__ h_ln, float* __restrict__ hn,
                           unsigned short* __restrict__ S_t, float* __restrict__ wm,
                           unsigned short* __restrict__ S2,
                           unsigned short* __restrict__ jobs){
  int blk = blockIdx.x, tid = threadIdx.x;
  if (blk < 256){                       // LN(h) + unit-norm: 4 rows/block
    int row = blk*4 + (tid >> 6);
    int d   = tid & 63;
    float x = h[row*DIN + d];
    float mean = wave_sum(x) * (1.f/64.f);
    float xm = x - mean;
    float var = wave_sum(xm*xm) * (1.f/64.f);
    float hl = xm * rsqrtf(var + 1e-5f) * g_in[d] + b_in[d];
    h_ln[row*DIN + d] = hl;
    float nrm = sqrtf(wave_sum(hl*hl));
    nrm = fmaxf(nrm, 1e-12f);
    hn[row*DIN + d] = hl / nrm;
  } else if (blk < 320){                // S_t in fragment order (R17 win)
    int o = blk - 256;
    int nt = o >> 4, colr = o & 15;
    for (int k = tid; k < KTOT; k += 256){
      float v;
      if (k < 64){
        v = ka_bw[o*64 + k];
      } else {
        int km = k - 64, dd = km >> 3, j = km & 7;
        float c = ka_c[(o*64 + dd)*8 + j];
        c = fminf(5.f, fmaxf(-5.f, c));
        v = c * ka_sw[o*64 + dd];
      }
      int s = k >> 5, grp = (k >> 3) & 3, e = k & 7;
      int lane = grp*16 + colr;
      S_t[((s*4 + nt)*64 + lane)*8 + e] = f2bf(v);
    }
  } else if (blk == 320){               // wm + job table
    if (tid < 64){
      float s = 0.f;
      for (int k = 0; k < 256; ++k) s += W_att[tid*256 + k];
      wm[tid] = s * (1.f/256.f);
    }
    const int offs[9] = {0,256,480,672,832,960,1056,1120,1152};
    for (int f = tid; f < NJOBS; f += 256){
      int t = 0;
      while (f >= offs[t+1]) ++t;       // n-tile 0..7
      int r = f - offs[t];
      int n = t*32 + r / (8 - t);
      int w = t + r % (8 - t);
      jobs[f] = (unsigned short)((n << 3) | w);
    }
  } else {                              // S2 fragment order (R18 win)
    int o = blk - 321;
    for (int kk = tid; kk < K2TOT; kk += 256){
      const float* bw; const float* sw; const float* cc;
      int k = kk;
      if (kk < KTOT){ bw = kp_bw; sw = kp_sw; cc = kp_c; }
      else          { bw = kd_bw; sw = kd_sw; cc = kd_c; k = kk - KTOT; }
      float v;
      if (k < 64){
        v = bw[o*64 + k];
      } else {
        int km = k - 64, d = km >> 3, j = km & 7;
        float c = cc[(o*64 + d)*8 + j];
        c = fminf(5.f, fmaxf(-5.f, c));
        v = c * sw[o*64 + d];
      }
      S2[((kk >> 3)*128 + o)*8 + (kk & 7)] = f2bf(v);
    }
  }
}

// ---------- kernel B: scores[b,n,m] — register-resident phase 0/1 ----------
// Grid 1152, 4-wave blocks, uniform wave-jobs (R21 structure). NEW: thread
// owns row lane>>1 / half lane&1; loads its 32 hn floats straight to
// registers (coalesced 16KB/wave), bf16-rounds once (same pk2 rounding ->
// bitwise-same values), computes LN sums and tanh from registers, writes
// LDS ONCE with final X. Removes 8 ds_writes + 16 ds_reads per thread and
// two LDS dependency chains vs R21. Phase 2 / epilogue unchanged.
__launch_bounds__(256, 4)
__global__ void k_scores(const float* __restrict__ hn,
                         const float* __restrict__ ln_p_g, const float* __restrict__ ln_p_b,
                         const unsigned short* __restrict__ S_t,
                         const float* __restrict__ wm,
                         const unsigned short* __restrict__ jobs,
                         float* __restrict__ scores){
  __shared__ unsigned short Xs[128 * XST16];   // 4 strips x 32 rows = 17408 B
  __shared__ float hnn_l[4][64];
  __shared__ float g_l[64], b_l[64];

  int blkid = blockIdx.x;
  int bb    = blkid / 288;
  int jb    = (blkid % 288) * 4;

  int tid  = threadIdx.x;
  int lane = tid & 63, wave = tid >> 6;   // 4 waves, all active
  int job  = jobs[jb + wave];
  int n    = job >> 3;
  int w    = job & 7;
  int sn   = n >> 5;
  int m0g  = w * 32;               // global m-strip base
  int lr0  = wave * 32;            // LDS strip base

  // ---- per-wave broadcast data (redundant same-value writes for g/b) ----
  g_l[lane] = ln_p_g[lane];
  b_l[lane] = ln_p_b[lane];
  hnn_l[wave][lane] = bf2f(f2bf(hn[(bb*NSEQ + n)*DIN + lane]));  // bf16-rounded: bitwise symmetry

  // ---- phase 0+1 merged: load own row-half to regs, LN+tanh, single LDS write ----
  {
    int r = lane >> 1, hh = lane & 1;       // r in [0,32) within strip
    const float* src = hn + (bb*NSEQ + m0g + r)*DIN + hh*32;
    uint2 W[8];
#pragma unroll
    for (int i = 0; i < 8; ++i){
      float4 v = *(const float4*)(src + i*4);
      W[i].x = pk2(v.x, v.y);
      W[i].y = pk2(v.z, v.w);
    }
    const float* hp = hnn_l[wave] + hh*32;
    float s1 = 0.f, s2 = 0.f;
#pragma unroll
    for (int i = 0; i < 8; ++i){
      float x0 = bf2f_lo(W[i].x), x1 = bf2f_hi(W[i].x), x2 = bf2f_lo(W[i].y), x3 = bf2f_hi(W[i].y);
      float p0 = x0*hp[i*4+0], p1 = x1*hp[i*4+1], p2 = x2*hp[i*4+2], p3 = x3*hp[i*4+3];
      s1 += (p0+p1) + (p2+p3);
      s2 = fmaf(p0,p0, fmaf(p1,p1, fmaf(p2,p2, fmaf(p3,p3, s2))));
    }
    s1 += __shfl_xor(s1, 1, 64);
    s2 += __shfl_xor(s2, 1, 64);
    float mean = s1 * (1.f/64.f);
    float var  = fmaxf(s2 * (1.f/64.f) - mean*mean, 0.f);
    float inv  = rsqrtf(var + 1e-5f);
    const float* gp = g_l + hh*32;
    const float* bp = b_l + hh*32;
    unsigned short* dst = Xs + (lr0 + r)*XST16 + hh*32;
#pragma unroll
    for (int i = 0; i < 8; ++i){
      float x0 = bf2f_lo(W[i].x), x1 = bf2f_hi(W[i].x), x2 = bf2f_lo(W[i].y), x3 = bf2f_hi(W[i].y);
      float t0 = fast_tanh((x0*hp[i*4+0] - mean)*inv*gp[i*4+0] + bp[i*4+0]);
      float t1 = fast_tanh((x1*hp[i*4+1] - mean)*inv*gp[i*4+1] + bp[i*4+1]);
      float t2 = fast_tanh((x2*hp[i*4+2] - mean)*inv*gp[i*4+2] + bp[i*4+2]);
      float t3 = fast_tanh((x3*hp[i*4+3] - mean)*inv*gp[i*4+3] + bp[i*4+3]);
      uint2 pk = { pk2(t0, t1), pk2(t2, t3) };
      *(uint2*)(dst + i*4) = pk;
    }
  }
  // same-wave LDS write->read ordering via lgkmcnt; no __syncthreads anywhere.

  // ---- phase 2: MFMA K-loop, fragment-order B from global ----
  int colr = lane & 15, grp = lane >> 4;
  const unsigned short* rowA = Xs + (lr0 + colr)*XST16;
  const unsigned short* rowB = Xs + (lr0 + 16 + colr)*XST16;
  const unsigned short* sfp  = S_t + lane*8;   // + (s*4+nt)*512 per fragment

  f32x4 acc[2][4];
#pragma unroll
  for (int a = 0; a < 2; ++a)
#pragma unroll
    for (int c = 0; c < 4; ++c){ f32x4 z = {0.f,0.f,0.f,0.f}; acc[a][c] = z; }

  // silu steps (k = 0..63): lane's 8 k-slots = 8 dims
#pragma unroll
  for (int s = 0; s < 2; ++s){
    int kw = s*32 + grp*8;
    bf16x8 bf[4];
#pragma unroll
    for (int nt = 0; nt < 4; ++nt)
      bf[nt] = *(const bf16x8*)(sfp + (s*4 + nt)*512);
    union { unsigned u[4]; bf16x8 v8; } a0, a1;
    uint2 wa0 = *(const uint2*)(rowA + kw), wa1 = *(const uint2*)(rowA + kw + 4);
    uint2 wb0 = *(const uint2*)(rowB + kw), wb1 = *(const uint2*)(rowB + kw + 4);
    a0.u[0] = pk2(silu_f(bf2f_lo(wa0.x)), silu_f(bf2f_hi(wa0.x)));
    a0.u[1] = pk2(silu_f(bf2f_lo(wa0.y)), silu_f(bf2f_hi(wa0.y)));
    a0.u[2] = pk2(silu_f(bf2f_lo(wa1.x)), silu_f(bf2f_hi(wa1.x)));
    a0.u[3] = pk2(silu_f(bf2f_lo(wa1.y)), silu_f(bf2f_hi(wa1.y)));
    a1.u[0] = pk2(silu_f(bf2f_lo(wb0.x)), silu_f(bf2f_hi(wb0.x)));
    a1.u[1] = pk2(silu_f(bf2f_lo(wb0.y)), silu_f(bf2f_hi(wb0.y)));
    a1.u[2] = pk2(silu_f(bf2f_lo(wb1.x)), silu_f(bf2f_hi(wb1.x)));
    a1.u[3] = pk2(silu_f(bf2f_lo(wb1.y)), silu_f(bf2f_hi(wb1.y)));
#pragma unroll
    for (int nt = 0; nt < 4; ++nt){
      acc[0][nt] = __builtin_amdgcn_mfma_f32_16x16x32_bf16(a0.v8, bf[nt], acc[0][nt], 0, 0, 0);
      acc[1][nt] = __builtin_amdgcn_mfma_f32_16x16x32_bf16(a1.v8, bf[nt], acc[1][nt], 0, 0, 0);
    }
  }

  // spline steps (k = 64..575): lane's 8 k-slots = one dim's 8 bases
#pragma unroll 4
  for (int s = 2; s < NSTEP; ++s){
    int d  = (s - 2)*4 + grp;
    bf16x8 bf[4];
#pragma unroll
    for (int nt = 0; nt < 4; ++nt)
      bf[nt] = *(const bf16x8*)(sfp + (s*4 + nt)*512);
    bf16x8 a0 = spline_pack(bf2f(rowA[d]));
    bf16x8 a1 = spline_pack(bf2f(rowB[d]));
#pragma unroll
    for (int nt = 0; nt < 4; ++nt){
      acc[0][nt] = __builtin_amdgcn_mfma_f32_16x16x32_bf16(a0, bf[nt], acc[0][nt], 0, 0, 0);
      acc[1][nt] = __builtin_amdgcn_mfma_f32_16x16x32_bf16(a1, bf[nt], acc[1][nt], 0, 0, 0);
    }
  }

  // ---- epilogue: score[m] = sum_o tanh(out[m][o]) * wm[o]; direct + transpose ----
  float wmv[4];
#pragma unroll
  for (int nt = 0; nt < 4; ++nt) wmv[nt] = wm[nt*16 + colr];

#pragma unroll
  for (int a = 0; a < 2; ++a){
    float sacc[4] = {0.f,0.f,0.f,0.f};
#pragma unroll
    for (int nt = 0; nt < 4; ++nt){
#pragma unroll
      for (int r = 0; r < 4; ++r)
        sacc[r] += fast_tanh(acc[a][nt][r]) * wmv[nt];
    }
#pragma unroll
    for (int off = 1; off < 16; off <<= 1){
#pragma unroll
      for (int r = 0; r < 4; ++r) sacc[r] += __shfl_xor(sacc[r], off, 64);
    }
    if (colr == 0){
      int mb   = m0g + a*16 + grp*4;
      int base = (bb*NSEQ + n)*NSEQ + mb;
      float4 v = { sacc[0], sacc[1], sacc[2], sacc[3] };
      *(float4*)&scores[base] = v;
      if (w > sn){                // diagonal strip covered by direct writes
        int tb = bb*NSEQ*NSEQ + n;
#pragma unroll
        for (int r = 0; r < 4; ++r)
          scores[tb + (mb + r)*NSEQ] = sacc[r];
      }
    }
  }
}

// ---------- kernel C: softmax + h_att + final KANs + BN (R21) ----------
__launch_bounds__(512, 4)
__global__ void k_smf(const float* __restrict__ scores,
                      const float* __restrict__ h_ln,
                      const unsigned short* __restrict__ S2,
                      const float* __restrict__ bn_g, const float* __restrict__ bn_b,
                      const float* __restrict__ bn_mean, const float* __restrict__ bn_var,
                      float* __restrict__ out){
  __shared__ float att[2][256];
  __shared__ float redm[2][4], reds[2][4];
  __shared__ float part[2][4][64];
  __shared__ float hatt[2][64];
  __shared__ float feat[2][K2TOT];
  __shared__ float pout[2][128];
  int row0 = blockIdx.x * 2;       // rows = b*256+n
  int tid = threadIdx.x, lane = tid & 63;
  int rw   = tid >> 8;             // row within block (0/1)
  int wv4  = (tid >> 6) & 3;       // wave within row (0..3)
  int t256 = tid & 255;            // 0..255 within row
  int row  = row0 + rw;

  // softmax over m: 256 threads/row, 1 element each
  float sc = scores[row*NSEQ + t256] * 0.125f;
  float mx = sc;
#pragma unroll
  for (int off = 1; off < 64; off <<= 1) mx = fmaxf(mx, __shfl_xor(mx, off, 64));
  if (lane == 0) redm[rw][wv4] = mx;
  __syncthreads();
  mx = fmaxf(fmaxf(redm[rw][0], redm[rw][1]), fmaxf(redm[rw][2], redm[rw][3]));
  float e = __expf(sc - mx);
  float es = wave_sum(e);
  if (lane == 0) reds[rw][wv4] = es;
  __syncthreads();
  float tot = (reds[rw][0] + reds[rw][1]) + (reds[rw][2] + reds[rw][3]);
  att[rw][t256] = e / tot;
  __syncthreads();

  // h_att = attn @ h_ln (4 waves per row; 64 m each)
  int hb = row & ~255;             // b*256
  float a2 = 0.f;
  for (int m = wv4*64; m < wv4*64 + 64; ++m)
    a2 += att[rw][m] * h_ln[(hb + m)*DIN + lane];
  part[rw][wv4][lane] = a2;
  __syncthreads();
  if (wv4 == 0)
    hatt[rw][lane] = (part[rw][0][lane] + part[rw][1][lane])
                   + (part[rw][2][lane] + part[rw][3][lane]);
  __syncthreads();

  // feature build: 2 rows x 128 jobs; threads with t256<128 do them
  if (t256 < 128){
    int src = t256 >> 6, dd = t256 & 63;
    float x = src ? h_ln[row*DIN + dd] : hatt[rw][dd];
    x = fast_tanh(x);
    int base = src * KTOT;
    feat[rw][base + dd] = silu_f(x);
    int fb = base + 64 + dd*8;
#pragma unroll
    for (int jj = 0; jj < 8; ++jj) feat[rw][fb + jj] = 0.f;
    int i; float wgt[4];
    spline_w(x, i, wgt);
#pragma unroll
    for (int k = 0; k < 4; ++k){
      int jj = i + k;
      if (jj < 8) feat[rw][fb + jj] = wgt[k];
    }
  }
  __syncthreads();

  // dot: thread (rw, half = t256>>7, o = t256&127); 72 chunks each
  int o = t256 & 127, half = t256 >> 7;
  const unsigned short* sp = S2 + o*8 + half*72*1024;
  const float* fp = feat[rw] + half*576;
  float acc = 0.f;
#pragma unroll 4
  for (int jj = 0; jj < 72; ++jj){
    uint4  w  = *(const uint4*)(sp + jj*1024);
    float4 f0 = *(const float4*)(fp + jj*8);
    float4 f1 = *(const float4*)(fp + jj*8 + 4);
    acc = fmaf(f0.x, bf2f_lo(w.x), acc);
    acc = fmaf(f0.y, bf2f_hi(w.x), acc);
    acc = fmaf(f0.z, bf2f_lo(w.y), acc);
    acc = fmaf(f0.w, bf2f_hi(w.y), acc);
    acc = fmaf(f1.x, bf2f_lo(w.z), acc);
    acc = fmaf(f1.y, bf2f_hi(w.z), acc);
    acc = fmaf(f1.z, bf2f_lo(w.w), acc);
    acc = fmaf(f1.w, bf2f_hi(w.w), acc);
  }
  if (half) pout[rw][o] = acc;
  __syncthreads();
  if (!half){
    float a = acc + pout[rw][o];
    float r = (a - bn_mean[o]) * rsqrtf(bn_var[o] + 1e-5f) * bn_g[o] + bn_b[o];
    out[row*DOUT + o] = r;
  }
}

extern "C" void kernel_launch(void* const* d_in, const int* in_sizes, int n_in,
                              void* d_out, int out_size, void* d_ws, size_t ws_size,
                              hipStream_t stream){
  (void)in_sizes; (void)n_in; (void)out_size; (void)ws_size;
  const float* h       = (const float*)d_in[0];
  const float* ln_in_g = (const float*)d_in[1];
  const float* ln_in_b = (const float*)d_in[2];
  const float* ln_p_g  = (const float*)d_in[3];
  const float* ln_p_b  = (const float*)d_in[4];
  const float* ka_bw   = (const float*)d_in[5];
  const float* ka_sw   = (const float*)d_in[6];
  const float* ka_c    = (const float*)d_in[7];
  const float* W_att   = (const float*)d_in[8];
  const float* kp_bw   = (const float*)d_in[9];
  const float* kp_sw   = (const float*)d_in[10];
  const float* kp_c    = (const float*)d_in[11];
  const float* kd_bw   = (const float*)d_in[12];
  const float* kd_sw   = (const float*)d_in[13];
  const float* kd_c    = (const float*)d_in[14];
  const float* bn_g    = (const float*)d_in[15];
  const float* bn_b    = (const float*)d_in[16];
  const float* bn_mean = (const float*)d_in[17];
  const float* bn_var  = (const float*)d_in[18];
  float* out = (float*)d_out;

  char* ws = (char*)d_ws;
  float*          h_ln   = (float*)(ws + 0);                        // 256 KB
  float*          hn     = (float*)(ws + 262144);                   // 256 KB
  unsigned short* S_t    = (unsigned short*)(ws + 524288);          // 72 KB (fragment order)
  float*          wm     = (float*)(ws + 598016);                   // 256 B
  float*          scores = (float*)(ws + 598272);                   // 1 MB
  unsigned short* jobs   = (unsigned short*)(ws + 1646848);         // 2.3 KB
  unsigned short* S2     = (unsigned short*)(ws + 1908992);         // 288 KB (fragment order)

  k_prep_all<<<449, 256, 0, stream>>>(h, ln_in_g, ln_in_b, ka_bw, ka_sw, ka_c, W_att,
                                      kp_bw, kp_sw, kp_c, kd_bw, kd_sw, kd_c,
                                      h_ln, hn, S_t, wm, S2, jobs);
  k_scores<<<1152, 256, 0, stream>>>(hn, ln_p_g, ln_p_b, S_t, wm, jobs, scores);
  k_smf<<<512, 512, 0, stream>>>(scores, h_ln, S2, bn_g, bn_b, bn_mean, bn_var, out);
}